// Round 1
// baseline (110.410 us; speedup 1.0000x reference)
//
#include <hip/hip_runtime.h>
#include <hip/hip_fp16.h>

#define GAT_ALPHA 0.2f
#define GAT_NEG_INF -9.0e15f

// k0: v_i[f] = sum_h W_i[f][h] * a_w[h]   (128 threads, 1 block)
__global__ void gat_precompute_vi(const float* __restrict__ Wi,
                                  const float* __restrict__ aw,
                                  float* __restrict__ vi) {
    int f = threadIdx.x;  // 128 threads
    float s = 0.f;
    #pragma unroll 8
    for (int h = 0; h < 128; ++h)
        s = fmaf(Wi[f * 128 + h], aw[h], s);
    vi[f] = s;
}

// k1: Wh16[n] = fp16(h[n] @ W_j); e2[n] = Wh[n]·a_j; e1[n] = h[n]·v_i + a_b
// Block = 256 thr (4 waves). W_j staged in 64KB LDS. Each wave handles 2
// nodes (one per 32-lane half); lane l32 owns output dims [4*l32, 4*l32+3].
// h[n][f] is read via same-address broadcast global loads (L1-resident row).
__global__ __launch_bounds__(256) void gat_transform(
    const float* __restrict__ h, const float* __restrict__ Wj,
    const float* __restrict__ aw, const float* __restrict__ ab,
    const float* __restrict__ vi,
    __half* __restrict__ Wh16, float* __restrict__ e1, float* __restrict__ e2,
    int N) {
    __shared__ float4 sW[128 * 32];  // exactly 64 KB: row f = 32 float4
    const float4* Wj4 = (const float4*)Wj;
    int t = threadIdx.x;
    #pragma unroll
    for (int i = 0; i < 16; ++i) sW[t + i * 256] = Wj4[t + i * 256];
    __syncthreads();

    const int wave = t >> 6, lane = t & 63, half = lane >> 5, l32 = lane & 31;
    const float abv = ab[0];
    const float4 viv = ((const float4*)vi)[l32];
    const float4 ajv = ((const float4*)(aw + 128))[l32];  // a_j chunk
    const float4* h4 = (const float4*)h;
    const int npairs = (N + 1) >> 1;

    for (int pair = blockIdx.x * 4 + wave; pair < npairs; pair += gridDim.x * 4) {
        int n = 2 * pair + half;
        bool ok = (n < N);
        int nc = ok ? n : 0;
        const float4* hrow = h4 + (size_t)nc * 32;
        float4 hreg = hrow[l32];  // lane-distributed copy for e1 reduction
        float ax = 0.f, ay = 0.f, az = 0.f, aw4 = 0.f;
        #pragma unroll 4
        for (int fb = 0; fb < 32; ++fb) {
            float4 hq = hrow[fb];  // broadcast within half-wave (L1 hit)
            float4 w0 = sW[(4 * fb + 0) * 32 + l32];
            float4 w1 = sW[(4 * fb + 1) * 32 + l32];
            float4 w2 = sW[(4 * fb + 2) * 32 + l32];
            float4 w3 = sW[(4 * fb + 3) * 32 + l32];
            ax = fmaf(hq.x, w0.x, ax); ay = fmaf(hq.x, w0.y, ay);
            az = fmaf(hq.x, w0.z, az); aw4 = fmaf(hq.x, w0.w, aw4);
            ax = fmaf(hq.y, w1.x, ax); ay = fmaf(hq.y, w1.y, ay);
            az = fmaf(hq.y, w1.z, az); aw4 = fmaf(hq.y, w1.w, aw4);
            ax = fmaf(hq.z, w2.x, ax); ay = fmaf(hq.z, w2.y, ay);
            az = fmaf(hq.z, w2.z, az); aw4 = fmaf(hq.z, w2.w, aw4);
            ax = fmaf(hq.w, w3.x, ax); ay = fmaf(hq.w, w3.y, ay);
            az = fmaf(hq.w, w3.z, az); aw4 = fmaf(hq.w, w3.w, aw4);
        }
        if (ok) {
            union { __half hh[4]; float2 f2; } u;
            u.hh[0] = __float2half(ax); u.hh[1] = __float2half(ay);
            u.hh[2] = __float2half(az); u.hh[3] = __float2half(aw4);
            *(float2*)(Wh16 + (size_t)n * 128 + 4 * l32) = u.f2;  // 8B coalesced
            // e2 partial from exact fp32 acc (matches reference precision)
            float pe2 = ax * ajv.x + ay * ajv.y + az * ajv.z + aw4 * ajv.w;
            float pe1 = hreg.x * viv.x + hreg.y * viv.y + hreg.z * viv.z + hreg.w * viv.w;
            #pragma unroll
            for (int mm = 1; mm < 32; mm <<= 1) {  // reduce within 32-lane half
                pe2 += __shfl_xor(pe2, mm);
                pe1 += __shfl_xor(pe1, mm);
            }
            if (l32 == 0) { e2[n] = pe2; e1[n] = pe1 + abv; }
        }
    }
}

// k2: per node (one wave): gather e2[idx], leaky_relu logits, softmax over 32
// via shuffles (both 32-lane halves hold identical copies), then gather 32
// fp16 Wh rows (256B each, 4B/lane) and weighted-sum into dims (2*lane,
// 2*lane+1). Output fp32.
__global__ __launch_bounds__(256) void gat_gather(
    const int* __restrict__ ctx, const float* __restrict__ e1,
    const float* __restrict__ e2, const __half* __restrict__ Wh16,
    float* __restrict__ out, int N) {
    int t = threadIdx.x;
    int wave = t >> 6, lane = t & 63, c = lane & 31;
    for (int n = blockIdx.x * 4 + wave; n < N; n += gridDim.x * 4) {
        int iv = ctx[n * 32 + c];
        bool valid = iv >= 0;
        int j = valid ? iv : 0;  // clamp so gather stays in-bounds
        float lg = e1[n] + e2[j];          // e1 already includes a_b
        lg = fmaxf(lg, GAT_ALPHA * lg);    // leaky_relu (alpha<1)
        lg = valid ? lg : GAT_NEG_INF;
        float m = lg;
        #pragma unroll
        for (int s = 16; s; s >>= 1) m = fmaxf(m, __shfl_xor(m, s));
        float p = valid ? __expf(lg - m) : 0.f;
        float ssum = p;
        #pragma unroll
        for (int s = 16; s; s >>= 1) ssum += __shfl_xor(ssum, s);
        p = (ssum > 0.f) ? p / ssum : 0.f;  // all-masked node -> zeros
        float a0 = 0.f, a1 = 0.f;
        #pragma unroll 16
        for (int cc = 0; cc < 32; ++cc) {
            float w = __shfl(p, cc);
            int jj = __shfl(j, cc);
            __half2 hv = *((const __half2*)(Wh16 + (size_t)jj * 128) + lane);
            float2 f2 = __half22float2(hv);
            a0 = fmaf(w, f2.x, a0);
            a1 = fmaf(w, f2.y, a1);
        }
        ((float2*)(out + (size_t)n * 128))[lane] = make_float2(a0, a1);
    }
}

extern "C" void kernel_launch(void* const* d_in, const int* in_sizes, int n_in,
                              void* d_out, int out_size, void* d_ws, size_t ws_size,
                              hipStream_t stream) {
    const float* h   = (const float*)d_in[0];
    const int*   ctx = (const int*)d_in[1];
    const float* Wi  = (const float*)d_in[2];
    const float* Wj  = (const float*)d_in[3];
    const float* aw  = (const float*)d_in[4];
    const float* ab  = (const float*)d_in[5];
    float* out = (float*)d_out;
    const int N = in_sizes[0] / 128;

    // workspace layout: vi[128] | pad[128] | e1[N] | e2[N] | Wh16[N*128] (fp16)
    float* vi = (float*)d_ws;
    float* e1 = vi + 256;
    float* e2 = e1 + N;
    __half* Wh16 = (__half*)(e2 + N);

    gat_precompute_vi<<<1, 128, 0, stream>>>(Wi, aw, vi);
    gat_transform<<<512, 256, 0, stream>>>(h, Wj, aw, ab, vi, Wh16, e1, e2, N);
    gat_gather<<<(N + 3) / 4, 256, 0, stream>>>(ctx, e1, e2, Wh16, out, N);
}

// Round 2
// 102.289 us; speedup vs baseline: 1.0794x; 1.0794x over previous
//
#include <hip/hip_runtime.h>
#include <hip/hip_fp16.h>

#define GAT_ALPHA 0.2f
#define GAT_NEG_INF -9.0e15f

typedef _Float16 half8_t __attribute__((ext_vector_type(8)));
typedef _Float16 half4_t __attribute__((ext_vector_type(4)));
typedef float f32x4 __attribute__((ext_vector_type(4)));

// k0: v_i[f] = sum_h W_i[f][h] * a_w[h]   (128 threads, 1 block)
__global__ void gat_precompute_vi(const float* __restrict__ Wi,
                                  const float* __restrict__ aw,
                                  float* __restrict__ vi) {
    int f = threadIdx.x;  // 128 threads
    float s = 0.f;
    #pragma unroll 8
    for (int h = 0; h < 128; ++h)
        s = fmaf(Wi[f * 128 + h], aw[h], s);
    vi[f] = s;
}

// k1: MFMA f16 GEMM. Wh16 = fp16(h @ W_j); e2 = Wh@a_j (from fp32 acc);
// e1 = h@vi + ab (from fp32 h in registers). One wave = one 16-node tile.
// A-frag: lane(m=lane&15, q=lane>>4) holds h[m][q*8+j+32s] (global loads,
// cvt to f16 in-reg). B-frag: W_j^T fp16 in LDS, row stride 136 halves
// (272 B: 16B-aligned, bank windows 4*((lane&7)+q) tile 32 banks evenly).
__global__ __launch_bounds__(256) void gat_transform_mfma(
    const float* __restrict__ h, const float* __restrict__ Wj,
    const float* __restrict__ aw, const float* __restrict__ ab,
    const float* __restrict__ vi,
    __half* __restrict__ Wh16, float* __restrict__ e1, float* __restrict__ e2,
    int N) {
    __shared__ _Float16 sWt[128 * 136];  // W_j^T, padded: 34816 B
    const int t = threadIdx.x;
    for (int i = t; i < 128 * 128; i += 256) {
        int k = i >> 7, n = i & 127;          // W_j[k][n] row-major read
        sWt[n * 136 + k] = (_Float16)Wj[i];   // transpose into LDS
    }
    __syncthreads();

    const int wave = t >> 6, lane = t & 63, q = lane >> 4, l16 = lane & 15;
    const float abv = ab[0];

    // vi chunk this lane consumes for e1: vi[s*32 + q*8 + j]
    float vir[4][8];
    {
        const float4* vi4 = (const float4*)vi;
        #pragma unroll
        for (int s = 0; s < 4; ++s) {
            float4 u0 = vi4[s * 8 + q * 2];
            float4 u1 = vi4[s * 8 + q * 2 + 1];
            vir[s][0] = u0.x; vir[s][1] = u0.y; vir[s][2] = u0.z; vir[s][3] = u0.w;
            vir[s][4] = u1.x; vir[s][5] = u1.y; vir[s][6] = u1.z; vir[s][7] = u1.w;
        }
    }
    // a_j value for this lane's output column in each of the 8 col-tiles
    float ajr[8];
    #pragma unroll
    for (int c = 0; c < 8; ++c) ajr[c] = aw[128 + c * 16 + l16];

    const int ntiles = (N + 15) >> 4;
    for (int tile = blockIdx.x * 4 + wave; tile < ntiles; tile += gridDim.x * 4) {
        const int base = tile << 4;
        int row = base + l16; if (row >= N) row = N - 1;  // clamp (N%16 tail)
        const float* hp = h + (size_t)row * 128 + q * 8;

        half8_t af[4];
        float pe1 = 0.f;  // fp32-exact partial of h[row]·vi
        #pragma unroll
        for (int s = 0; s < 4; ++s) {
            float4 f0 = *(const float4*)(hp + s * 32);
            float4 f1 = *(const float4*)(hp + s * 32 + 4);
            pe1 = fmaf(f0.x, vir[s][0], pe1); pe1 = fmaf(f0.y, vir[s][1], pe1);
            pe1 = fmaf(f0.z, vir[s][2], pe1); pe1 = fmaf(f0.w, vir[s][3], pe1);
            pe1 = fmaf(f1.x, vir[s][4], pe1); pe1 = fmaf(f1.y, vir[s][5], pe1);
            pe1 = fmaf(f1.z, vir[s][6], pe1); pe1 = fmaf(f1.w, vir[s][7], pe1);
            half8_t a;
            a[0] = (_Float16)f0.x; a[1] = (_Float16)f0.y;
            a[2] = (_Float16)f0.z; a[3] = (_Float16)f0.w;
            a[4] = (_Float16)f1.x; a[5] = (_Float16)f1.y;
            a[6] = (_Float16)f1.z; a[7] = (_Float16)f1.w;
            af[s] = a;
        }

        f32x4 acc[8];
        #pragma unroll
        for (int c = 0; c < 8; ++c) { f32x4 z = {0.f, 0.f, 0.f, 0.f}; acc[c] = z; }

        const _Float16* wbase = sWt + l16 * 136 + q * 8;
        #pragma unroll
        for (int s = 0; s < 4; ++s) {
            #pragma unroll
            for (int c = 0; c < 8; ++c) {
                half8_t bf = *(const half8_t*)(wbase + c * (16 * 136) + s * 32);
                acc[c] = __builtin_amdgcn_mfma_f32_16x16x32_f16(af[s], bf, acc[c], 0, 0, 0);
            }
        }

        // Epilogue. D layout: col = c*16 + l16, row(node) = base + q*4 + r.
        const bool full = (base + 16 <= N);
        float pe2[4] = {0.f, 0.f, 0.f, 0.f};
        #pragma unroll
        for (int c = 0; c < 8; ++c) {
            #pragma unroll
            for (int r = 0; r < 4; ++r) {
                float v = acc[c][r];
                pe2[r] = fmaf(v, ajr[c], pe2[r]);
                int rr = base + q * 4 + r;
                if (full || rr < N)
                    Wh16[(size_t)rr * 128 + (c * 16 + l16)] = __float2half(v);
            }
        }
        #pragma unroll
        for (int r = 0; r < 4; ++r) {  // reduce over the 16 cols held in-quad
            pe2[r] += __shfl_xor(pe2[r], 1);
            pe2[r] += __shfl_xor(pe2[r], 2);
            pe2[r] += __shfl_xor(pe2[r], 4);
            pe2[r] += __shfl_xor(pe2[r], 8);
        }
        if (l16 == 0) {
            #pragma unroll
            for (int r = 0; r < 4; ++r) {
                int rr = base + q * 4 + r;
                if (rr < N) e2[rr] = pe2[r];
            }
        }
        pe1 += __shfl_xor(pe1, 16);  // reduce over q (k-chunks)
        pe1 += __shfl_xor(pe1, 32);
        if (lane < 16) {
            int rr = base + lane;
            if (rr < N) e1[rr] = pe1 + abv;
        }
    }
}

// k2: 2 nodes per wave (one per 32-lane half). Half-local softmax via
// width-32 shuffles; gather 32 fp16 rows (8 B/lane, coalesced 256 B per
// half), fma-mix accumulate fp32, float4 store.
__global__ __launch_bounds__(256) void gat_gather2(
    const int* __restrict__ ctx, const float* __restrict__ e1,
    const float* __restrict__ e2, const __half* __restrict__ Wh16,
    float* __restrict__ out, int N) {
    const int t = threadIdx.x;
    const int wave = t >> 6, lane = t & 63, hf = lane >> 5, l = lane & 31;
    const int pair = blockIdx.x * 4 + wave;
    if (pair * 2 >= N) return;  // wave-uniform exit
    const int n = pair * 2 + hf;
    const bool okn = (n < N);
    const int nn = okn ? n : (N - 1);

    const int iv = ctx[(size_t)nn * 32 + l];
    const bool valid = (iv >= 0);
    const int j = valid ? iv : 0;
    float lg = e1[nn] + e2[j];          // e1 includes a_b
    lg = fmaxf(lg, GAT_ALPHA * lg);     // leaky_relu
    lg = valid ? lg : GAT_NEG_INF;
    float m = lg;
    #pragma unroll
    for (int s = 16; s; s >>= 1) m = fmaxf(m, __shfl_xor(m, s));  // half-local
    float p = valid ? __expf(lg - m) : 0.f;
    float ss = p;
    #pragma unroll
    for (int s = 16; s; s >>= 1) ss += __shfl_xor(ss, s);
    p = (ss > 0.f) ? p / ss : 0.f;

    const int offB = j << 8;  // byte offset of row j in Wh16 (256 B rows)
    float a0 = 0.f, a1 = 0.f, a2 = 0.f, a3 = 0.f;
    const char* wb = (const char*)Wh16 + (size_t)(l * 8);
    #pragma unroll 8
    for (int cc = 0; cc < 32; ++cc) {
        int off = __shfl(offB, cc, 32);   // half-local broadcast
        float w = __shfl(p, cc, 32);
        half4_t hv = *(const half4_t*)(wb + off);  // 8 B coalesced
        a0 = fmaf(w, (float)hv[0], a0);
        a1 = fmaf(w, (float)hv[1], a1);
        a2 = fmaf(w, (float)hv[2], a2);
        a3 = fmaf(w, (float)hv[3], a3);
    }
    if (okn) {
        float4 o; o.x = a0; o.y = a1; o.z = a2; o.w = a3;
        ((float4*)(out + (size_t)n * 128))[l] = o;
    }
}

extern "C" void kernel_launch(void* const* d_in, const int* in_sizes, int n_in,
                              void* d_out, int out_size, void* d_ws, size_t ws_size,
                              hipStream_t stream) {
    const float* h   = (const float*)d_in[0];
    const int*   ctx = (const int*)d_in[1];
    const float* Wi  = (const float*)d_in[2];
    const float* Wj  = (const float*)d_in[3];
    const float* aw  = (const float*)d_in[4];
    const float* ab  = (const float*)d_in[5];
    float* out = (float*)d_out;
    const int N = in_sizes[0] / 128;

    // workspace: vi[128] | pad[128] | e1[N] | e2[N] | Wh16[N*128] fp16
    float* vi = (float*)d_ws;
    float* e1 = vi + 256;
    float* e2 = e1 + N;
    __half* Wh16 = (__half*)(e2 + N);

    const int ntiles = (N + 15) >> 4;
    int g1 = (ntiles + 3) / 4; if (g1 > 160) g1 = 160;
    const int pairs = (N + 1) / 2;

    gat_precompute_vi<<<1, 128, 0, stream>>>(Wi, aw, vi);
    gat_transform_mfma<<<g1, 256, 0, stream>>>(h, Wj, aw, ab, vi, Wh16, e1, e2, N);
    gat_gather2<<<(pairs + 3) / 4, 256, 0, stream>>>(ctx, e1, e2, Wh16, out, N);
}

// Round 3
// 101.549 us; speedup vs baseline: 1.0873x; 1.0073x over previous
//
#include <hip/hip_runtime.h>
#include <hip/hip_fp16.h>

#define GAT_ALPHA 0.2f
#define GAT_NEG_INF -9.0e15f

typedef _Float16 half8_t __attribute__((ext_vector_type(8)));
typedef float f32x4 __attribute__((ext_vector_type(4)));

// k1: MFMA f16 GEMM. Wh16 = fp16(h @ W_j); e2 = Wh@a_j (fp32 acc);
// e1 = h@vi + ab (fp32, vi = W_i@a_i computed in the prologue into LDS).
// One wave = one 16-node tile. A-frag from global fp32 (cvt in-reg);
// B-frag: W_j^T fp16 in LDS, row stride 136 halves.
__global__ __launch_bounds__(256) void gat_transform_mfma(
    const float* __restrict__ h, const float* __restrict__ Wi,
    const float* __restrict__ Wj, const float* __restrict__ aw,
    const float* __restrict__ ab,
    __half* __restrict__ Wh16, float* __restrict__ e1, float* __restrict__ e2,
    int N) {
    __shared__ _Float16 sWt[128 * 136];  // W_j^T, padded: 34816 B
    __shared__ float svi[128];           // vi = W_i @ a_i
    const int t = threadIdx.x;

    // prologue 1: vi (threads 0..127; ~64KB of W_i from L2, broadcast a_w)
    if (t < 128) {
        const float4* wrow = (const float4*)(Wi + (size_t)t * 128);
        const float4* a4 = (const float4*)aw;  // a_i = aw[0:128]
        float s = 0.f;
        #pragma unroll
        for (int i = 0; i < 32; ++i) {
            float4 w = wrow[i], a = a4[i];
            s = fmaf(w.x, a.x, s); s = fmaf(w.y, a.y, s);
            s = fmaf(w.z, a.z, s); s = fmaf(w.w, a.w, s);
        }
        svi[t] = s;
    }
    // prologue 2: W_j^T into LDS as fp16
    for (int i = t; i < 128 * 128; i += 256) {
        int k = i >> 7, n = i & 127;          // W_j[k][n] row-major read
        sWt[n * 136 + k] = (_Float16)Wj[i];
    }
    __syncthreads();

    const int wave = t >> 6, lane = t & 63, q = lane >> 4, l16 = lane & 15;
    const float abv = ab[0];

    // vi chunk this lane consumes for e1: vi[s*32 + q*8 + j]
    float vir[4][8];
    #pragma unroll
    for (int s = 0; s < 4; ++s) {
        float4 u0 = *(const float4*)(svi + s * 32 + q * 8);
        float4 u1 = *(const float4*)(svi + s * 32 + q * 8 + 4);
        vir[s][0] = u0.x; vir[s][1] = u0.y; vir[s][2] = u0.z; vir[s][3] = u0.w;
        vir[s][4] = u1.x; vir[s][5] = u1.y; vir[s][6] = u1.z; vir[s][7] = u1.w;
    }
    // a_j value for this lane's output column in each of the 8 col-tiles
    float ajr[8];
    #pragma unroll
    for (int c = 0; c < 8; ++c) ajr[c] = aw[128 + c * 16 + l16];

    const int ntiles = (N + 15) >> 4;
    for (int tile = blockIdx.x * 4 + wave; tile < ntiles; tile += gridDim.x * 4) {
        const int base = tile << 4;
        int row = base + l16; if (row >= N) row = N - 1;  // clamp tail
        const float* hp = h + (size_t)row * 128 + q * 8;

        half8_t af[4];
        float pe1 = 0.f;  // fp32-exact partial of h[row]·vi
        #pragma unroll
        for (int s = 0; s < 4; ++s) {
            float4 f0 = *(const float4*)(hp + s * 32);
            float4 f1 = *(const float4*)(hp + s * 32 + 4);
            pe1 = fmaf(f0.x, vir[s][0], pe1); pe1 = fmaf(f0.y, vir[s][1], pe1);
            pe1 = fmaf(f0.z, vir[s][2], pe1); pe1 = fmaf(f0.w, vir[s][3], pe1);
            pe1 = fmaf(f1.x, vir[s][4], pe1); pe1 = fmaf(f1.y, vir[s][5], pe1);
            pe1 = fmaf(f1.z, vir[s][6], pe1); pe1 = fmaf(f1.w, vir[s][7], pe1);
            half8_t a;
            a[0] = (_Float16)f0.x; a[1] = (_Float16)f0.y;
            a[2] = (_Float16)f0.z; a[3] = (_Float16)f0.w;
            a[4] = (_Float16)f1.x; a[5] = (_Float16)f1.y;
            a[6] = (_Float16)f1.z; a[7] = (_Float16)f1.w;
            af[s] = a;
        }

        f32x4 acc[8];
        #pragma unroll
        for (int c = 0; c < 8; ++c) { f32x4 z = {0.f, 0.f, 0.f, 0.f}; acc[c] = z; }

        const _Float16* wbase = sWt + l16 * 136 + q * 8;
        #pragma unroll
        for (int s = 0; s < 4; ++s) {
            #pragma unroll
            for (int c = 0; c < 8; ++c) {
                half8_t bf = *(const half8_t*)(wbase + c * (16 * 136) + s * 32);
                acc[c] = __builtin_amdgcn_mfma_f32_16x16x32_f16(af[s], bf, acc[c], 0, 0, 0);
            }
        }

        // Epilogue. D layout: col = c*16 + l16, row(node) = base + q*4 + r.
        const bool full = (base + 16 <= N);
        float pe2[4] = {0.f, 0.f, 0.f, 0.f};
        #pragma unroll
        for (int c = 0; c < 8; ++c) {
            #pragma unroll
            for (int r = 0; r < 4; ++r) {
                float v = acc[c][r];
                pe2[r] = fmaf(v, ajr[c], pe2[r]);
                int rr = base + q * 4 + r;
                if (full || rr < N)
                    Wh16[(size_t)rr * 128 + (c * 16 + l16)] = __float2half(v);
            }
        }
        #pragma unroll
        for (int r = 0; r < 4; ++r) {  // reduce over the 16 cols held in-quad
            pe2[r] += __shfl_xor(pe2[r], 1);
            pe2[r] += __shfl_xor(pe2[r], 2);
            pe2[r] += __shfl_xor(pe2[r], 4);
            pe2[r] += __shfl_xor(pe2[r], 8);
        }
        if (l16 == 0) {
            #pragma unroll
            for (int r = 0; r < 4; ++r) {
                int rr = base + q * 4 + r;
                if (rr < N) e2[rr] = pe2[r];
            }
        }
        pe1 += __shfl_xor(pe1, 16);  // reduce over q (k-chunks)
        pe1 += __shfl_xor(pe1, 32);
        if (lane < 16) {
            int rr = base + lane;
            if (rr < N) e1[rr] = pe1 + abv;
        }
    }
}

// k2: 4 nodes per wave (one per 16-lane quarter). Each lane owns 2
// neighbors (int2 ctx load) and 8 output dims (half8 = 16 B row chunk).
// Quarter-local softmax via width-16 shuffles; 16 B/lane gathers.
__global__ __launch_bounds__(256) void gat_gather4(
    const int* __restrict__ ctx, const float* __restrict__ e1,
    const float* __restrict__ e2, const __half* __restrict__ Wh16,
    float* __restrict__ out, int N) {
    const int t = threadIdx.x;
    const int wave = t >> 6, lane = t & 63, qid = lane >> 4, l = lane & 15;
    const int widx = blockIdx.x * 4 + wave;
    if (widx * 4 >= N) return;  // wave-uniform exit
    const int n = widx * 4 + qid;
    const bool okn = (n < N);
    const int nn = okn ? n : (N - 1);

    int2 ij = ((const int2*)(ctx + (size_t)nn * 32))[l];  // neighbors 2l,2l+1
    const bool v0 = (ij.x >= 0), v1 = (ij.y >= 0);
    const int j0 = v0 ? ij.x : 0, j1 = v1 ? ij.y : 0;
    const float eb = e1[nn];  // includes a_b
    float lg0 = eb + e2[j0], lg1 = eb + e2[j1];
    lg0 = fmaxf(lg0, GAT_ALPHA * lg0);  // leaky_relu (alpha<1)
    lg1 = fmaxf(lg1, GAT_ALPHA * lg1);
    lg0 = v0 ? lg0 : GAT_NEG_INF;
    lg1 = v1 ? lg1 : GAT_NEG_INF;
    float m = fmaxf(lg0, lg1);
    #pragma unroll
    for (int s = 8; s; s >>= 1) m = fmaxf(m, __shfl_xor(m, s, 16));
    float p0 = v0 ? __expf(lg0 - m) : 0.f;
    float p1 = v1 ? __expf(lg1 - m) : 0.f;
    float ss = p0 + p1;
    #pragma unroll
    for (int s = 8; s; s >>= 1) ss += __shfl_xor(ss, s, 16);
    const float inv = (ss > 0.f) ? __frcp_rn(ss) : 0.f;
    p0 *= inv; p1 *= inv;

    const int o0 = j0 << 8, o1 = j1 << 8;  // byte offset of 256 B rows
    float a0 = 0.f, a1 = 0.f, a2 = 0.f, a3 = 0.f;
    float a4 = 0.f, a5 = 0.f, a6 = 0.f, a7 = 0.f;
    const char* wb = (const char*)Wh16 + (size_t)(l * 16);
    #pragma unroll 8
    for (int cc = 0; cc < 32; ++cc) {
        const int src = cc >> 1;
        float w   = __shfl((cc & 1) ? p1 : p0, src, 16);
        int   off = __shfl((cc & 1) ? o1 : o0, src, 16);
        half8_t hv = *(const half8_t*)(wb + off);  // 16 B, quarter = 256 B row
        a0 = fmaf(w, (float)hv[0], a0); a1 = fmaf(w, (float)hv[1], a1);
        a2 = fmaf(w, (float)hv[2], a2); a3 = fmaf(w, (float)hv[3], a3);
        a4 = fmaf(w, (float)hv[4], a4); a5 = fmaf(w, (float)hv[5], a5);
        a6 = fmaf(w, (float)hv[6], a6); a7 = fmaf(w, (float)hv[7], a7);
    }
    if (okn) {
        float4* orow = (float4*)(out + (size_t)n * 128);
        float4 u; u.x = a0; u.y = a1; u.z = a2; u.w = a3;
        float4 v; v.x = a4; v.y = a5; v.z = a6; v.w = a7;
        orow[2 * l] = u;
        orow[2 * l + 1] = v;
    }
}

extern "C" void kernel_launch(void* const* d_in, const int* in_sizes, int n_in,
                              void* d_out, int out_size, void* d_ws, size_t ws_size,
                              hipStream_t stream) {
    const float* h   = (const float*)d_in[0];
    const int*   ctx = (const int*)d_in[1];
    const float* Wi  = (const float*)d_in[2];
    const float* Wj  = (const float*)d_in[3];
    const float* aw  = (const float*)d_in[4];
    const float* ab  = (const float*)d_in[5];
    float* out = (float*)d_out;
    const int N = in_sizes[0] / 128;

    // workspace: e1[N] | e2[N] | Wh16[N*128] fp16
    float* e1 = (float*)d_ws;
    float* e2 = e1 + N;
    __half* Wh16 = (__half*)(e2 + N);

    const int ntiles = (N + 15) >> 4;       // 16-node MFMA tiles
    const int g1 = (ntiles + 3) / 4;        // 4 waves/block, 1 tile/wave
    const int nquad = (N + 3) / 4;          // 4 nodes/wave
    const int g2 = (nquad + 3) / 4;

    gat_transform_mfma<<<g1, 256, 0, stream>>>(h, Wi, Wj, aw, ab, Wh16, e1, e2, N);
    gat_gather4<<<g2, 256, 0, stream>>>(ctx, e1, e2, Wh16, out, N);
}